// Round 9
// baseline (308.372 us; speedup 1.0000x reference)
//
#include <hip/hip_runtime.h>
#include <hip/hip_bf16.h>
#include <cstdint>

// ============================================================================
// MultiHeadSelfAttention: B=8 T=1024 D=1024 H=16 dh=64. fp32 in / fp32 out.
// R16 = R15 resubmit (R15 bench died to container-infra failure, no counters;
// audit clean: LDS 69KB < 160KB (R14 ran 128KB), all LDS/global indices
// in-bounds, uniform barriers, proven GEMM unchanged, cvt ranges exact).
// R15 (R14 post-mortem: 8-phase GEMM1 null — 384 blocks = 1.5 CU-fills tail
// + K=1024 short-prologue; reverted to R13's proven 2-phase GEMM):
//  - attn KVBLK 64->128: one barrier pair per 128 tokens (16 total, was 32).
//    sK[128][72] (two sigma-mapped 64-halves), sVT[64][136] (d x token),
//    sP[128][136]. QK+softmax per 64-half (sacc/av stay [4]); PV spans 128.
//    LDS 69KB (2 blk/CU cap; measured residency was ~1.5 anyway).
//  - launch cut 8->5: GEMM epilogues read fp32 bias directly (both bias-cvt
//    launches dropped); inputs+W_qkv cvt merged into one kernel.
//  - GEMM1/GEMM3 = R13's 2-phase 128^2, 512thr, dbuf, counted vmcnt(4), raw
//    barriers, T2 both-sides swizzle, L2-aware XCD-chunk traversal.
// ws (64MiB): Qp@0, Kp@16MiB, Vt@32MiB, aout@48MiB (each [8192][1024] bf16).
// d_out scratch phase 1: ib_bf@0 (16MiB), wq_bf@16MiB (6MiB).
// After attn: wo_bf overwrites dead Qp@0. GEMM3 writes d_out fp32 last.
// ============================================================================

using bf16 = __hip_bfloat16;
typedef __attribute__((ext_vector_type(8))) short short8;
typedef __attribute__((ext_vector_type(4))) short short4v;
typedef __attribute__((ext_vector_type(4))) float floatx4;
typedef __attribute__((ext_vector_type(2))) unsigned int uint2v;

#define B_    8
#define T_    1024
#define D_    1024
#define H_    16
#define PROJW 3072

__device__ __forceinline__ void gl2lds16(const void* g, void* l) {
  __builtin_amdgcn_global_load_lds(
      (const __attribute__((address_space(1))) void*)g,
      (__attribute__((address_space(3))) void*)l,
      16, 0, 0);
}

__device__ __forceinline__ unsigned short f2b_bits(float f) {
  return __builtin_bit_cast(unsigned short, __float2bfloat16(f));
}

// raw v_exp_f32 (1 ulp), bypassing the OCML exp2f range-fixup path
__device__ __forceinline__ float fast_exp2(float x) {
#if __has_builtin(__builtin_amdgcn_exp2f)
  return __builtin_amdgcn_exp2f(x);
#else
  float r;
  asm("v_exp_f32 %0, %1\ns_nop 0" : "=v"(r) : "v"(x));
  return r;
#endif
}

// ---------------------------------------------------------------------------
// fp32 -> bf16 elementwise converts (quads), RNE
// ---------------------------------------------------------------------------
__device__ __forceinline__ void cvt_quad(const float* s, bf16* d, int i) {
  floatx4 f = *(const floatx4*)(s + i);
  short4v h;
  h[0] = f2b_bits(f[0]); h[1] = f2b_bits(f[1]);
  h[2] = f2b_bits(f[2]); h[3] = f2b_bits(f[3]);
  *(short4v*)(d + i) = h;
}

__global__ __launch_bounds__(256)
void cvt_f32_bf16(const float* __restrict__ src, bf16* __restrict__ dst, int n) {
  int i = (blockIdx.x * 256 + threadIdx.x) * 4;
  if (i < n) cvt_quad(src, dst, i);
}

// merged: region A (nq_a quads) then region B (rest of grid)
__global__ __launch_bounds__(256)
void cvt2_f32_bf16(const float* __restrict__ sa, bf16* __restrict__ da, int nq_a,
                   const float* __restrict__ sb, bf16* __restrict__ db) {
  int q = blockIdx.x * 256 + threadIdx.x;
  if (q < nq_a) cvt_quad(sa, da, q * 4);
  else          cvt_quad(sb, db, (q - nq_a) * 4);
}

// ---------------------------------------------------------------------------
// GEMM core (R13-proven): C = A[M,K] * Bm[N,K]^T + bias(fp32), bf16 DMA
// staging, fp32 accum. EPI=1: C fp32 (final output). EPI=2: QKV split
// epilogue (Qp/Kp token-major, Vt transposed [b][h][d][t]).
// 128x128 tile, BK=64, 512 threads: 8 waves x (32x64) of 16x16x32 MFMA.
// dbuf slots, deep prefetch, counted vmcnt(4), raw barriers, T2 swizzle
// (source-side + read-side), L2-aware XCD-chunk traversal (BNB=4).
// ---------------------------------------------------------------------------
template<int EPI>
__global__ __launch_bounds__(512)
void gemm_bt_bias(const bf16* __restrict__ A, const bf16* __restrict__ Bm,
                  const float* __restrict__ bias, void* __restrict__ C0,
                  void* __restrict__ C1, void* __restrict__ C2,
                  int M, int N, int K)
{
  __shared__ __align__(16) unsigned short sA[2][128 * 64];
  __shared__ __align__(16) unsigned short sB[2][128 * 64];

  const int tid  = threadIdx.x;
  const int lane = tid & 63;
  const int wv   = tid >> 6;          // 0..7
  const int quad = lane >> 4;
  const int l16  = lane & 15;
  const int wm   = wv >> 1;           // 0..3: 32-row band
  const int wn   = wv & 1;            // 0..1: 64-col band

  // L2-aware XCD-chunked traversal (GEMM1: nwg=1536 gx=24; GEMM3: 512/8).
  const int gx   = gridDim.x;
  const int nwg  = gx * gridDim.y;
  const int bidl = blockIdx.y * gx + blockIdx.x;
  const int xcd  = bidl & 7;
  const int c    = bidl >> 3;
  const int cpx  = nwg >> 3;
  const int R    = cpx / gx;          // bm rows per XCD
  const int nb   = c / (R * 4);
  const int rem  = c % (R * 4);
  const int bm   = xcd * R + (rem >> 2);
  const int bn   = nb * 4 + (rem & 3);

  floatx4 acc[2][4];
#pragma unroll
  for (int i = 0; i < 2; ++i)
#pragma unroll
    for (int j = 0; j < 4; ++j) acc[i][j] = (floatx4){0.f, 0.f, 0.f, 0.f};

  // staging: thread covers LDS bytes o = it*8192 + wv*1024 + lane*16. LDS
  // dest LINEAR; global source pre-swizzled col_byte ^= (row&7)<<4 (rule #21).
  const int o_base = wv * 1024 + lane * 16;
  const bf16* gA[2];
  const bf16* gB[2];
#pragma unroll
  for (int it = 0; it < 2; ++it) {
    int o   = it * 8192 + o_base;
    int row = o >> 7;
    int col = ((o & 127) ^ ((row & 7) << 4)) >> 1;
    gA[it] = A  + (size_t)(bm * 128 + row) * K + col;
    gB[it] = Bm + (size_t)(bn * 128 + row) * K + col;
  }

  const int NT = K >> 6;
#pragma unroll
  for (int it = 0; it < 2; ++it)
    gl2lds16(gA[it], &sA[0][(it * 8192 + wv * 1024) >> 1]);
#pragma unroll
  for (int it = 0; it < 2; ++it)
    gl2lds16(gB[it], &sB[0][(it * 8192 + wv * 1024) >> 1]);

  const int swx = (l16 & 7) << 3;   // read-side element XOR

  for (int t = 0; t < NT; ++t) {
    const int s = t & 1;
    if (t + 1 < NT) {
#pragma unroll
      for (int it = 0; it < 2; ++it)
        gl2lds16(gA[it] + (size_t)(t + 1) * 64, &sA[s ^ 1][(it * 8192 + wv * 1024) >> 1]);
#pragma unroll
      for (int it = 0; it < 2; ++it)
        gl2lds16(gB[it] + (size_t)(t + 1) * 64, &sB[s ^ 1][(it * 8192 + wv * 1024) >> 1]);
      __builtin_amdgcn_sched_barrier(0);
      asm volatile("s_waitcnt vmcnt(4)" ::: "memory");
    } else {
      asm volatile("s_waitcnt vmcnt(0)" ::: "memory");
    }
    __builtin_amdgcn_s_barrier();
    __builtin_amdgcn_sched_barrier(0);

#pragma unroll
    for (int kk = 0; kk < 64; kk += 32) {
      short8 a_[2], b_[4];
#pragma unroll
      for (int i = 0; i < 2; ++i)
        a_[i] = *(const short8*)&sA[s][(wm * 32 + i * 16 + l16) * 64 + ((kk + quad * 8) ^ swx)];
#pragma unroll
      for (int j = 0; j < 4; ++j)
        b_[j] = *(const short8*)&sB[s][(wn * 64 + j * 16 + l16) * 64 + ((kk + quad * 8) ^ swx)];
#pragma unroll
      for (int i = 0; i < 2; ++i)
#pragma unroll
        for (int j = 0; j < 4; ++j)
          acc[i][j] = __builtin_amdgcn_mfma_f32_16x16x32_bf16(a_[i], b_[j], acc[i][j], 0, 0, 0);
    }

    __builtin_amdgcn_sched_barrier(0);
    __builtin_amdgcn_s_barrier();
  }

  if (EPI == 1) {
#pragma unroll
    for (int j = 0; j < 4; ++j) {
      const int colg = bn * 128 + wn * 64 + j * 16 + l16;
      const float bv = bias[colg];
#pragma unroll
      for (int i = 0; i < 2; ++i)
#pragma unroll
        for (int r = 0; r < 4; ++r) {
          int rowg = bm * 128 + wm * 32 + i * 16 + quad * 4 + r;
          ((float*)C0)[(size_t)rowg * N + colg] = acc[i][j][r] + bv;
        }
    }
  } else {
    const int region = bn >> 3;
    if (region < 2) {
      bf16* dst = (bf16*)(region == 0 ? C0 : C1);
#pragma unroll
      for (int j = 0; j < 4; ++j) {
        const int colg = bn * 128 + wn * 64 + j * 16 + l16;
        const int colr = colg & 1023;
        const float bv = bias[colg];
#pragma unroll
        for (int i = 0; i < 2; ++i)
#pragma unroll
          for (int r = 0; r < 4; ++r) {
            int rowg = bm * 128 + wm * 32 + i * 16 + quad * 4 + r;
            dst[(size_t)rowg * 1024 + colr] = __float2bfloat16(acc[i][j][r] + bv);
          }
      }
    } else {
      bf16* vt = (bf16*)C2;
#pragma unroll
      for (int j = 0; j < 4; ++j) {
        const int colg = bn * 128 + wn * 64 + j * 16 + l16;
        const int d  = colg & 63;
        const int hh = (colg >> 6) & 15;
        const float bv = bias[colg];
#pragma unroll
        for (int i = 0; i < 2; ++i) {
          int rowg0 = bm * 128 + wm * 32 + i * 16 + quad * 4;
          int bb = rowg0 >> 10, t0 = rowg0 & 1023;
          short4v pk;
#pragma unroll
          for (int r = 0; r < 4; ++r) pk[r] = (short)f2b_bits(acc[i][j][r] + bv);
          *(short4v*)&vt[((size_t)(bb * 16 + hh) << 16) + ((size_t)d << 10) + t0] = pk;
        }
      }
    }
  }
}

// ---------------------------------------------------------------------------
// Fused attention, KVBLK=128. grid (16,8,8), 512 threads (8 waves x
// 16 q-rows), LDS 69KB: sK[128][72] (rows n: half=n>>6, token = kt*128 +
// (n>>6)*64 + sigma(n&63), sigma(m)=(m&15)*4+(m>>4)); sVT[64][136]
// (d x 128 tokens); sP[128][136]. Per iteration: one barrier pair, stage
// 128 tokens (reg-staged, 4x b128/thread), QK+softmax per 64-half
// (logical score col = hh*64 + l16*4 + j), PV+ones-L over 128 cols.
// fast_exp2, cvt_pk pack, folded scale, b=XCD work swizzle. 8 iterations.
// ---------------------------------------------------------------------------
__global__ __launch_bounds__(512)
void attn_fused(const bf16* __restrict__ Qp, const bf16* __restrict__ Kp,
                const bf16* __restrict__ Vt, const float* __restrict__ adj,
                const float* __restrict__ mask, bf16* __restrict__ aout)
{
  __shared__ __align__(16) unsigned short sK [128 * 72];
  __shared__ __align__(16) unsigned short sVT[64 * 136];
  __shared__ __align__(16) unsigned short sP [128 * 136];

  const int tid  = threadIdx.x;
  const int lane = tid & 63;
  const int wv   = tid >> 6;          // 0..7
  const int quad = lane >> 4;
  const int l16  = lane & 15;

  // work swizzle: adj-sharing (b,qt) groups contiguous per XCD, K/V[b] local
  const int bid  = blockIdx.x + 16 * (blockIdx.y + 8 * blockIdx.z);
  const int b    = bid & 7;
  const int slot = bid >> 3;
  const int h    = slot & 15;
  const int qt   = slot >> 4;

  // Q fragments: rows qt*128 + wv*16 + l16, k = kk + quad*8 + [0..7]
  const bf16* qbase = Qp + (size_t)(b * T_ + qt * 128 + wv * 16 + l16) * 1024 + h * 64 + quad * 8;
  const short8 aq0 = *(const short8*)qbase;
  const short8 aq1 = *(const short8*)(qbase + 32);

  // staging: 512 threads cover 64 rows x 8 chunks; each thread handles both
  // 64-token halves (sK rows srow, srow+64; sVT cols chunk, chunk+64).
  const int srow  = tid >> 3;                          // 0..63
  const int chunk = (tid & 7) * 8;
  const int sig = ((srow & 15) << 2) | (srow >> 4);
  const bf16* kb0 = Kp + (size_t)(b * T_ + sig) * 1024 + h * 64 + chunk;       // +kt<<17
  const bf16* kb1 = kb0 + (size_t)64 * 1024;                                   // token +64
  const bf16* vb0 = Vt + ((size_t)(b * 16 + h) << 16) + ((size_t)srow << 10) + chunk; // +kt*128
  const bf16* vb1 = vb0 + 64;

  // adj/mask row pointers
  const float* mb = mask + b * T_ + l16 * 4;
  const float* adjr[4];
#pragma unroll
  for (int r = 0; r < 4; ++r)
    adjr[r] = adj + ((size_t)b * T_ + qt * 128 + wv * 16 + quad * 4 + r) * T_ + l16 * 4;

  // preload kt=0 staging registers
  short8 kr0 = *(const short8*)kb0;
  short8 kr1 = *(const short8*)kb1;
  short8 vr0 = *(const short8*)vb0;
  short8 vr1 = *(const short8*)vb1;

  // bf16 1.0 fragment for L row-sums via MFMA
  short8 ones8;
#pragma unroll
  for (int i = 0; i < 8; ++i) ones8[i] = (short)0x3F80;

  floatx4 oacc[4];
#pragma unroll
  for (int d = 0; d < 4; ++d) oacc[d] = (floatx4){0.f, 0.f, 0.f, 0.f};
  floatx4 Lacc = (floatx4){0.f, 0.f, 0.f, 0.f};

  const float SC = 0.125f * 1.44269504088896f;   // (1/sqrt(dh)) * log2(e)

  for (int kt = 0; kt < 8; ++kt) {
    __syncthreads();   // sync1: all waves done reading sK/sVT of prev iter
    *(short8*)&sK [srow * 72 + chunk]        = kr0;
    *(short8*)&sK [(srow + 64) * 72 + chunk] = kr1;
    *(short8*)&sVT[srow * 136 + chunk]       = vr0;
    *(short8*)&sVT[srow * 136 + chunk + 64]  = vr1;
    __syncthreads();   // sync2: staging visible

    // prefetch next iteration (VMEM overlaps compute below)
    {
      int nk = kt < 7 ? kt + 1 : 7;
      kr0 = *(const short8*)(kb0 + ((size_t)nk << 17));
      kr1 = *(const short8*)(kb1 + ((size_t)nk << 17));
      vr0 = *(const short8*)(vb0 + (nk << 7));
      vr1 = *(const short8*)(vb1 + (nk << 7));
    }

    // per 64-token half: S = Q K^T, softmax, pack into sP
#pragma unroll
    for (int hh = 0; hh < 2; ++hh) {
      floatx4 mk4 = *(const floatx4*)(mb + kt * 128 + hh * 64);
      floatx4 av[4];
#pragma unroll
      for (int r = 0; r < 4; ++r)
        av[r] = *(const floatx4*)(adjr[r] + kt * 128 + hh * 64);
      floatx4 cjv, offv;
#pragma unroll
      for (int j = 0; j < 4; ++j) {
        cjv[j]  = mk4[j] * SC;
        offv[j] = (mk4[j] == 0.f) ? -1e30f : 0.f;
      }

      floatx4 sacc[4];
#pragma unroll
      for (int j = 0; j < 4; ++j) sacc[j] = (floatx4){0.f, 0.f, 0.f, 0.f};
      __builtin_amdgcn_s_setprio(1);
#pragma unroll
      for (int kk = 0; kk < 64; kk += 32) {
        short8 aq = kk ? aq1 : aq0;
#pragma unroll
        for (int j = 0; j < 4; ++j) {
          short8 bk = *(const short8*)&sK[(hh * 64 + j * 16 + l16) * 72 + kk + quad * 8];
          sacc[j] = __builtin_amdgcn_mfma_f32_16x16x32_bf16(aq, bk, sacc[j], 0, 0, 0);
        }
      }
      __builtin_amdgcn_s_setprio(0);

#pragma unroll
      for (int r = 0; r < 4; ++r) {
        floatx4 avc = av[r] * cjv;
        float p[4];
#pragma unroll
        for (int j = 0; j < 4; ++j) {
          float z = fminf(fmaf(sacc[j][r], avc[j], offv[j]), 100.f);
          p[j] = fast_exp2(z);
        }
        unsigned w0, w1;
        asm("v_cvt_pk_bf16_f32 %0, %1, %2" : "=v"(w0) : "v"(p[0]), "v"(p[1]));
        asm("v_cvt_pk_bf16_f32 %0, %1, %2" : "=v"(w1) : "v"(p[2]), "v"(p[3]));
        uint2v pw; pw[0] = w0; pw[1] = w1;
        *(uint2v*)&sP[(wv * 16 + quad * 4 + r) * 136 + hh * 64 + l16 * 4] = pw;
      }
    }

    // sP rows wave-local; same-wave DS is HW-ordered. Stop compiler reorder:
    __asm__ __volatile__("" ::: "memory");

    // O += P V ; L += P * ones  (128 cols)
    __builtin_amdgcn_s_setprio(1);
#pragma unroll
    for (int kk = 0; kk < 128; kk += 32) {
      short8 ap = *(const short8*)&sP[(wv * 16 + l16) * 136 + kk + quad * 8];
      Lacc = __builtin_amdgcn_mfma_f32_16x16x32_bf16(ap, ones8, Lacc, 0, 0, 0);
#pragma unroll
      for (int d = 0; d < 4; ++d) {
        short8 bv = *(const short8*)&sVT[(d * 16 + l16) * 136 + kk + quad * 8];
        oacc[d] = __builtin_amdgcn_mfma_f32_16x16x32_bf16(ap, bv, oacc[d], 0, 0, 0);
      }
    }
    __builtin_amdgcn_s_setprio(0);
  }

  // epilogue: Lacc[r] holds the full row sum (every col identical)
#pragma unroll
  for (int d = 0; d < 4; ++d) {
#pragma unroll
    for (int r = 0; r < 4; ++r) {
      int qrow = qt * 128 + wv * 16 + quad * 4 + r;
      float val = oacc[d][r] / (Lacc[r] + 1e-13f);
      aout[(size_t)(b * T_ + qrow) * 1024 + h * 64 + d * 16 + l16] = __float2bfloat16(val);
    }
  }
}

// ---------------------------------------------------------------------------
extern "C" void kernel_launch(void* const* d_in, const int* in_sizes, int n_in,
                              void* d_out, int out_size, void* d_ws, size_t ws_size,
                              hipStream_t stream) {
  const float* inputs = (const float*)d_in[0];   // [8,1024,1024]
  const float* mask   = (const float*)d_in[1];   // [8,1024]
  const float* adj    = (const float*)d_in[2];   // [8,1024,1024]
  const float* W_qkv  = (const float*)d_in[3];   // [3072,1024]
  const float* b_qkv  = (const float*)d_in[4];   // [3072]
  const float* W_out  = (const float*)d_in[5];   // [1024,1024]
  const float* b_out  = (const float*)d_in[6];   // [1024]

  const size_t SEG = (size_t)8192 * 1024;        // 16 MiB bf16 segments
  bf16* Qp   = (bf16*)d_ws;                      // @0
  bf16* Kp   = Qp + SEG;                         // @16MiB
  bf16* Vt   = Kp + SEG;                         // @32MiB
  bf16* aout = Vt + SEG;                         // @48MiB
  bf16* wo_bf = Qp;                              // Qp dead after attn

  // d_out as phase-1 scratch (32MiB fp32 region, dead until GEMM3)
  bf16* ib_bf = (bf16*)d_out;                    // 16MiB
  bf16* wq_bf = ib_bf + SEG;                     // 6MiB

  dim3 blk(256);
  // merged cvt: inputs (2M quads) + W_qkv (768K quads) = 11264 blocks
  cvt2_f32_bf16<<<dim3((8192 * 1024 + 3072 * 1024) / 4 / 256), blk, 0, stream>>>(
      inputs, ib_bf, 8192 * 1024 / 4, W_qkv, wq_bf);
  // QKV projection with split epilogue (Qp, Kp, Vt); fp32 bias direct
  gemm_bt_bias<2><<<dim3(PROJW / 128, (B_ * T_) / 128), dim3(512), 0, stream>>>(
      ib_bf, wq_bf, b_qkv, Qp, Kp, Vt, B_ * T_, PROJW, D_);
  // fused attention (512 threads, 128 q-rows, KVBLK=128)
  attn_fused<<<dim3(H_, T_ / 128, B_), dim3(512), 0, stream>>>(Qp, Kp, Vt, adj, mask, aout);
  // output projection weights into dead Qp region
  cvt_f32_bf16<<<dim3(1024 * 1024 / 4 / 256), blk, 0, stream>>>(W_out, wo_bf, 1024 * 1024);
  // output projection: C fp32 -> d_out; fp32 bias direct
  gemm_bt_bias<1><<<dim3(D_ / 128, (B_ * T_) / 128), dim3(512), 0, stream>>>(
      aout, wo_bf, b_out, d_out, nullptr, nullptr, B_ * T_, D_, D_);
}

// Round 10
// 266.164 us; speedup vs baseline: 1.1586x; 1.1586x over previous
//
#include <hip/hip_runtime.h>
#include <hip/hip_bf16.h>
#include <cstdint>

// ============================================================================
// MultiHeadSelfAttention: B=8 T=1024 D=1024 H=16 dh=64. fp32 in / fp32 out.
// R17 (R16 post-mortem: KVBLK=128 regressed attn 87.8->116us — 69KB LDS
// halved residency to 2 blk/CU, occupancy 38->22%, all pipes dropped
// proportionally; attn's regime is TLP-hiding, residency > barrier
// amortization):
//  - attn reverted verbatim to the R11/R13-measured 87.8us version:
//    KVBLK=64, sK/sVT[64][72], sP[128][72], 36KB LDS (4 blk/CU),
//    512 thr / 128 q-rows, ones-MFMA L, setprio, cvt_pk pack, fast_exp2,
//    folded scale, b=XCD work swizzle.
//  - GEMM1/GEMM3: R13-proven 2-phase 128^2, 512thr, dbuf, counted vmcnt(4),
//    raw barriers, T2 both-sides swizzle, L2-aware XCD-chunk traversal;
//    fp32 bias direct (R16-verified).
//  - launch cut kept: merged inputs+W_qkv cvt, no bias cvt. 5 launches.
// ws (64MiB): Qp@0, Kp@16MiB, Vt@32MiB, aout@48MiB (each [8192][1024] bf16).
// d_out scratch phase 1: ib_bf@0 (16MiB), wq_bf@16MiB (6MiB).
// After attn: wo_bf overwrites dead Qp@0. GEMM3 writes d_out fp32 last.
// ============================================================================

using bf16 = __hip_bfloat16;
typedef __attribute__((ext_vector_type(8))) short short8;
typedef __attribute__((ext_vector_type(4))) short short4v;
typedef __attribute__((ext_vector_type(4))) float floatx4;
typedef __attribute__((ext_vector_type(2))) unsigned int uint2v;

#define B_    8
#define T_    1024
#define D_    1024
#define H_    16
#define PROJW 3072

__device__ __forceinline__ void gl2lds16(const void* g, void* l) {
  __builtin_amdgcn_global_load_lds(
      (const __attribute__((address_space(1))) void*)g,
      (__attribute__((address_space(3))) void*)l,
      16, 0, 0);
}

__device__ __forceinline__ unsigned short f2b_bits(float f) {
  return __builtin_bit_cast(unsigned short, __float2bfloat16(f));
}

// raw v_exp_f32 (1 ulp), bypassing the OCML exp2f range-fixup path
__device__ __forceinline__ float fast_exp2(float x) {
#if __has_builtin(__builtin_amdgcn_exp2f)
  return __builtin_amdgcn_exp2f(x);
#else
  float r;
  asm("v_exp_f32 %0, %1\ns_nop 0" : "=v"(r) : "v"(x));
  return r;
#endif
}

// ---------------------------------------------------------------------------
// fp32 -> bf16 elementwise converts (quads), RNE
// ---------------------------------------------------------------------------
__device__ __forceinline__ void cvt_quad(const float* s, bf16* d, int i) {
  floatx4 f = *(const floatx4*)(s + i);
  short4v h;
  h[0] = f2b_bits(f[0]); h[1] = f2b_bits(f[1]);
  h[2] = f2b_bits(f[2]); h[3] = f2b_bits(f[3]);
  *(short4v*)(d + i) = h;
}

__global__ __launch_bounds__(256)
void cvt_f32_bf16(const float* __restrict__ src, bf16* __restrict__ dst, int n) {
  int i = (blockIdx.x * 256 + threadIdx.x) * 4;
  if (i < n) cvt_quad(src, dst, i);
}

// merged: region A (nq_a quads) then region B (rest of grid)
__global__ __launch_bounds__(256)
void cvt2_f32_bf16(const float* __restrict__ sa, bf16* __restrict__ da, int nq_a,
                   const float* __restrict__ sb, bf16* __restrict__ db) {
  int q = blockIdx.x * 256 + threadIdx.x;
  if (q < nq_a) cvt_quad(sa, da, q * 4);
  else          cvt_quad(sb, db, (q - nq_a) * 4);
}

// ---------------------------------------------------------------------------
// GEMM core (R13-proven): C = A[M,K] * Bm[N,K]^T + bias(fp32), bf16 DMA
// staging, fp32 accum. EPI=1: C fp32 (final output). EPI=2: QKV split
// epilogue (Qp/Kp token-major, Vt transposed [b][h][d][t]).
// 128x128 tile, BK=64, 512 threads: 8 waves x (32x64) of 16x16x32 MFMA.
// dbuf slots, deep prefetch, counted vmcnt(4), raw barriers, T2 swizzle
// (source-side + read-side), L2-aware XCD-chunk traversal (BNB=4).
// ---------------------------------------------------------------------------
template<int EPI>
__global__ __launch_bounds__(512)
void gemm_bt_bias(const bf16* __restrict__ A, const bf16* __restrict__ Bm,
                  const float* __restrict__ bias, void* __restrict__ C0,
                  void* __restrict__ C1, void* __restrict__ C2,
                  int M, int N, int K)
{
  __shared__ __align__(16) unsigned short sA[2][128 * 64];
  __shared__ __align__(16) unsigned short sB[2][128 * 64];

  const int tid  = threadIdx.x;
  const int lane = tid & 63;
  const int wv   = tid >> 6;          // 0..7
  const int quad = lane >> 4;
  const int l16  = lane & 15;
  const int wm   = wv >> 1;           // 0..3: 32-row band
  const int wn   = wv & 1;            // 0..1: 64-col band

  // L2-aware XCD-chunked traversal (GEMM1: nwg=1536 gx=24; GEMM3: 512/8).
  const int gx   = gridDim.x;
  const int nwg  = gx * gridDim.y;
  const int bidl = blockIdx.y * gx + blockIdx.x;
  const int xcd  = bidl & 7;
  const int c    = bidl >> 3;
  const int cpx  = nwg >> 3;
  const int R    = cpx / gx;          // bm rows per XCD
  const int nb   = c / (R * 4);
  const int rem  = c % (R * 4);
  const int bm   = xcd * R + (rem >> 2);
  const int bn   = nb * 4 + (rem & 3);

  floatx4 acc[2][4];
#pragma unroll
  for (int i = 0; i < 2; ++i)
#pragma unroll
    for (int j = 0; j < 4; ++j) acc[i][j] = (floatx4){0.f, 0.f, 0.f, 0.f};

  // staging: thread covers LDS bytes o = it*8192 + wv*1024 + lane*16. LDS
  // dest LINEAR; global source pre-swizzled col_byte ^= (row&7)<<4 (rule #21).
  const int o_base = wv * 1024 + lane * 16;
  const bf16* gA[2];
  const bf16* gB[2];
#pragma unroll
  for (int it = 0; it < 2; ++it) {
    int o   = it * 8192 + o_base;
    int row = o >> 7;
    int col = ((o & 127) ^ ((row & 7) << 4)) >> 1;
    gA[it] = A  + (size_t)(bm * 128 + row) * K + col;
    gB[it] = Bm + (size_t)(bn * 128 + row) * K + col;
  }

  const int NT = K >> 6;
#pragma unroll
  for (int it = 0; it < 2; ++it)
    gl2lds16(gA[it], &sA[0][(it * 8192 + wv * 1024) >> 1]);
#pragma unroll
  for (int it = 0; it < 2; ++it)
    gl2lds16(gB[it], &sB[0][(it * 8192 + wv * 1024) >> 1]);

  const int swx = (l16 & 7) << 3;   // read-side element XOR

  for (int t = 0; t < NT; ++t) {
    const int s = t & 1;
    if (t + 1 < NT) {
#pragma unroll
      for (int it = 0; it < 2; ++it)
        gl2lds16(gA[it] + (size_t)(t + 1) * 64, &sA[s ^ 1][(it * 8192 + wv * 1024) >> 1]);
#pragma unroll
      for (int it = 0; it < 2; ++it)
        gl2lds16(gB[it] + (size_t)(t + 1) * 64, &sB[s ^ 1][(it * 8192 + wv * 1024) >> 1]);
      __builtin_amdgcn_sched_barrier(0);
      asm volatile("s_waitcnt vmcnt(4)" ::: "memory");
    } else {
      asm volatile("s_waitcnt vmcnt(0)" ::: "memory");
    }
    __builtin_amdgcn_s_barrier();
    __builtin_amdgcn_sched_barrier(0);

#pragma unroll
    for (int kk = 0; kk < 64; kk += 32) {
      short8 a_[2], b_[4];
#pragma unroll
      for (int i = 0; i < 2; ++i)
        a_[i] = *(const short8*)&sA[s][(wm * 32 + i * 16 + l16) * 64 + ((kk + quad * 8) ^ swx)];
#pragma unroll
      for (int j = 0; j < 4; ++j)
        b_[j] = *(const short8*)&sB[s][(wn * 64 + j * 16 + l16) * 64 + ((kk + quad * 8) ^ swx)];
#pragma unroll
      for (int i = 0; i < 2; ++i)
#pragma unroll
        for (int j = 0; j < 4; ++j)
          acc[i][j] = __builtin_amdgcn_mfma_f32_16x16x32_bf16(a_[i], b_[j], acc[i][j], 0, 0, 0);
    }

    __builtin_amdgcn_sched_barrier(0);
    __builtin_amdgcn_s_barrier();
  }

  if (EPI == 1) {
#pragma unroll
    for (int j = 0; j < 4; ++j) {
      const int colg = bn * 128 + wn * 64 + j * 16 + l16;
      const float bv = bias[colg];
#pragma unroll
      for (int i = 0; i < 2; ++i)
#pragma unroll
        for (int r = 0; r < 4; ++r) {
          int rowg = bm * 128 + wm * 32 + i * 16 + quad * 4 + r;
          ((float*)C0)[(size_t)rowg * N + colg] = acc[i][j][r] + bv;
        }
    }
  } else {
    const int region = bn >> 3;
    if (region < 2) {
      bf16* dst = (bf16*)(region == 0 ? C0 : C1);
#pragma unroll
      for (int j = 0; j < 4; ++j) {
        const int colg = bn * 128 + wn * 64 + j * 16 + l16;
        const int colr = colg & 1023;
        const float bv = bias[colg];
#pragma unroll
        for (int i = 0; i < 2; ++i)
#pragma unroll
          for (int r = 0; r < 4; ++r) {
            int rowg = bm * 128 + wm * 32 + i * 16 + quad * 4 + r;
            dst[(size_t)rowg * 1024 + colr] = __float2bfloat16(acc[i][j][r] + bv);
          }
      }
    } else {
      bf16* vt = (bf16*)C2;
#pragma unroll
      for (int j = 0; j < 4; ++j) {
        const int colg = bn * 128 + wn * 64 + j * 16 + l16;
        const int d  = colg & 63;
        const int hh = (colg >> 6) & 15;
        const float bv = bias[colg];
#pragma unroll
        for (int i = 0; i < 2; ++i) {
          int rowg0 = bm * 128 + wm * 32 + i * 16 + quad * 4;
          int bb = rowg0 >> 10, t0 = rowg0 & 1023;
          short4v pk;
#pragma unroll
          for (int r = 0; r < 4; ++r) pk[r] = (short)f2b_bits(acc[i][j][r] + bv);
          *(short4v*)&vt[((size_t)(bb * 16 + hh) << 16) + ((size_t)d << 10) + t0] = pk;
        }
      }
    }
  }
}

// ---------------------------------------------------------------------------
// Fused attention (R11/R13-measured 87.8us version). grid = (16, 8, 8),
// 512 threads (8 waves x 16 q-rows), LDS 36.0KB. Work swizzle: bid ->
// b=bid&7 (XCD), h=(bid>>3)&15 (fastest, adj-sharing blocks contiguous on
// one XCD), qt=bid>>7. Q fragments in registers (loop-invariant). K and V^T
// register-staged into stride-72 LDS, software-pipelined across kt.
// sigma(n)=(n&15)*4+(n>>4) on K rows => logical score col = l16*4+j:
// float4 adj/mask loads. p=fast_exp2(clamp(fma(sacc, avc, off))) with
// avc = av*cjv (folded scale); pack via v_cvt_pk_bf16_f32 (RNE) pairs,
// b64 sP stores. L row-sums via ones-column MFMA accumulated across kt.
// ---------------------------------------------------------------------------
__global__ __launch_bounds__(512)
void attn_fused(const bf16* __restrict__ Qp, const bf16* __restrict__ Kp,
                const bf16* __restrict__ Vt, const float* __restrict__ adj,
                const float* __restrict__ mask, bf16* __restrict__ aout)
{
  __shared__ __align__(16) unsigned short sK[64 * 72];
  __shared__ __align__(16) unsigned short sVT[64 * 72];
  __shared__ __align__(16) unsigned short sP[128 * 72];

  const int tid  = threadIdx.x;
  const int lane = tid & 63;
  const int wv   = tid >> 6;          // 0..7
  const int quad = lane >> 4;
  const int l16  = lane & 15;

  // work swizzle: adj-sharing (b,qt) groups contiguous per XCD, K/V[b] local
  const int bid  = blockIdx.x + 16 * (blockIdx.y + 8 * blockIdx.z);
  const int b    = bid & 7;
  const int slot = bid >> 3;
  const int h    = slot & 15;
  const int qt   = slot >> 4;

  // Q fragments: rows qt*128 + wv*16 + l16, k = kk + quad*8 + [0..7]
  const bf16* qbase = Qp + (size_t)(b * T_ + qt * 128 + wv * 16 + l16) * 1024 + h * 64 + quad * 8;
  const short8 aq0 = *(const short8*)qbase;
  const short8 aq1 = *(const short8*)(qbase + 32);

  // staging: 512 threads cover 64 rows x 8 chunks, one 16B chunk each
  const int srow  = tid >> 3;                          // 0..63
  const int chunk = (tid & 7) * 8;
  const int sig = ((srow & 15) << 2) | (srow >> 4);    // token offset for sK row
  const bf16* kb = Kp + (size_t)(b * T_ + sig) * 1024 + h * 64 + chunk;  // +kt<<16
  const bf16* vb = Vt + ((size_t)(b * 16 + h) << 16) + ((size_t)srow << 10) + chunk; // +kt*64

  // adj/mask row pointers
  const float* mb = mask + b * T_ + l16 * 4;
  const float* adjr[4];
#pragma unroll
  for (int r = 0; r < 4; ++r)
    adjr[r] = adj + ((size_t)b * T_ + qt * 128 + wv * 16 + quad * 4 + r) * T_ + l16 * 4;

  // preload kt=0 staging registers
  short8 kr = *(const short8*)kb;
  short8 vr = *(const short8*)vb;

  // bf16 1.0 fragment for L row-sums via MFMA
  short8 ones8;
#pragma unroll
  for (int i = 0; i < 8; ++i) ones8[i] = (short)0x3F80;

  floatx4 oacc[4];
#pragma unroll
  for (int d = 0; d < 4; ++d) oacc[d] = (floatx4){0.f, 0.f, 0.f, 0.f};
  floatx4 Lacc = (floatx4){0.f, 0.f, 0.f, 0.f};

  const float SC = 0.125f * 1.44269504088896f;   // (1/sqrt(dh)) * log2(e)

  for (int kt = 0; kt < 16; ++kt) {
    // adj/mask for this tile (logical cols kt*64 + l16*4 + {0..3})
    floatx4 av[4];
    floatx4 mk4 = *(const floatx4*)(mb + kt * 64);
#pragma unroll
    for (int r = 0; r < 4; ++r) av[r] = *(const floatx4*)(adjr[r] + kt * 64);
    floatx4 cjv, offv;
#pragma unroll
    for (int j = 0; j < 4; ++j) {
      cjv[j]  = mk4[j] * SC;
      offv[j] = (mk4[j] == 0.f) ? -1e30f : 0.f;
    }

    __syncthreads();   // sync1: all waves done reading sK/sVT of prev kt
    *(short8*)&sK [srow * 72 + chunk] = kr;
    *(short8*)&sVT[srow * 72 + chunk] = vr;
    __syncthreads();   // sync2: staging visible

    // prefetch next kt's staging registers (VMEM overlaps compute below)
    {
      int nk = kt < 15 ? kt + 1 : 15;
      kr = *(const short8*)(kb + ((size_t)nk << 16));
      vr = *(const short8*)(vb + (nk << 6));
    }

    // S = Q K^T  (sacc[j][r]: row wv*16+quad*4+r, logical col l16*4+j)
    floatx4 sacc[4];
#pragma unroll
    for (int j = 0; j < 4; ++j) sacc[j] = (floatx4){0.f, 0.f, 0.f, 0.f};
    __builtin_amdgcn_s_setprio(1);
#pragma unroll
    for (int kk = 0; kk < 64; kk += 32) {
      short8 aq = kk ? aq1 : aq0;
#pragma unroll
      for (int j = 0; j < 4; ++j) {
        short8 bk = *(const short8*)&sK[(j * 16 + l16) * 72 + kk + quad * 8];
        sacc[j] = __builtin_amdgcn_mfma_f32_16x16x32_bf16(aq, bk, sacc[j], 0, 0, 0);
      }
    }
    __builtin_amdgcn_s_setprio(0);

    // p = fast_exp2(clamp(fma(sacc, avc, off))); pack via v_cvt_pk_bf16_f32
#pragma unroll
    for (int r = 0; r < 4; ++r) {
      floatx4 avc = av[r] * cjv;      // folded adj*mask*SC (pk-pairable)
      float p[4];
#pragma unroll
      for (int j = 0; j < 4; ++j) {
        float z = fminf(fmaf(sacc[j][r], avc[j], offv[j]), 100.f);
        p[j] = fast_exp2(z);
      }
      unsigned w0, w1;
      asm("v_cvt_pk_bf16_f32 %0, %1, %2" : "=v"(w0) : "v"(p[0]), "v"(p[1]));
      asm("v_cvt_pk_bf16_f32 %0, %1, %2" : "=v"(w1) : "v"(p[2]), "v"(p[3]));
      uint2v pw; pw[0] = w0; pw[1] = w1;
      *(uint2v*)&sP[(wv * 16 + quad * 4 + r) * 72 + l16 * 4] = pw;
    }

    // sP rows wave-local; same-wave DS is HW-ordered. Stop compiler reorder:
    __asm__ __volatile__("" ::: "memory");

    // O += P V ; L += P * ones
    __builtin_amdgcn_s_setprio(1);
#pragma unroll
    for (int kk = 0; kk < 64; kk += 32) {
      short8 ap = *(const short8*)&sP[(wv * 16 + l16) * 72 + kk + quad * 8];
      Lacc = __builtin_amdgcn_mfma_f32_16x16x32_bf16(ap, ones8, Lacc, 0, 0, 0);
#pragma unroll
      for (int d = 0; d < 4; ++d) {
        short8 bv = *(const short8*)&sVT[(d * 16 + l16) * 72 + kk + quad * 8];
        oacc[d] = __builtin_amdgcn_mfma_f32_16x16x32_bf16(ap, bv, oacc[d], 0, 0, 0);
      }
    }
    __builtin_amdgcn_s_setprio(0);
  }

  // epilogue: Lacc[r] already holds the full row sum (every col identical)
#pragma unroll
  for (int d = 0; d < 4; ++d) {
#pragma unroll
    for (int r = 0; r < 4; ++r) {
      int qrow = qt * 128 + wv * 16 + quad * 4 + r;
      float val = oacc[d][r] / (Lacc[r] + 1e-13f);
      aout[(size_t)(b * T_ + qrow) * 1024 + h * 64 + d * 16 + l16] = __float2bfloat16(val);
    }
  }
}

// ---------------------------------------------------------------------------
extern "C" void kernel_launch(void* const* d_in, const int* in_sizes, int n_in,
                              void* d_out, int out_size, void* d_ws, size_t ws_size,
                              hipStream_t stream) {
  const float* inputs = (const float*)d_in[0];   // [8,1024,1024]
  const float* mask   = (const float*)d_in[1];   // [8,1024]
  const float* adj    = (const float*)d_in[2];   // [8,1024,1024]
  const float* W_qkv  = (const float*)d_in[3];   // [3072,1024]
  const float* b_qkv  = (const float*)d_in[4];   // [3072]
  const float* W_out  = (const float*)d_in[5];   // [1024,1024]
  const float* b_out  = (const float*)d_in[6];   // [1024]

  const size_t SEG = (size_t)8192 * 1024;        // 16 MiB bf16 segments
  bf16* Qp   = (bf16*)d_ws;                      // @0
  bf16* Kp   = Qp + SEG;                         // @16MiB
  bf16* Vt   = Kp + SEG;                         // @32MiB
  bf16* aout = Vt + SEG;                         // @48MiB
  bf16* wo_bf = Qp;                              // Qp dead after attn

  // d_out as phase-1 scratch (32MiB fp32 region, dead until GEMM3)
  bf16* ib_bf = (bf16*)d_out;                    // 16MiB
  bf16* wq_bf = ib_bf + SEG;                     // 6MiB

  dim3 blk(256);
  // merged cvt: inputs (2M quads) + W_qkv (768K quads) = 11264 blocks
  cvt2_f32_bf16<<<dim3((8192 * 1024 + 3072 * 1024) / 4 / 256), blk, 0, stream>>>(
      inputs, ib_bf, 8192 * 1024 / 4, W_qkv, wq_bf);
  // QKV projection with split epilogue (Qp, Kp, Vt); fp32 bias direct
  gemm_bt_bias<2><<<dim3(PROJW / 128, (B_ * T_) / 128), dim3(512), 0, stream>>>(
      ib_bf, wq_bf, b_qkv, Qp, Kp, Vt, B_ * T_, PROJW, D_);
  // fused attention (512 threads, 128 q-rows, KVBLK=64)
  attn_fused<<<dim3(H_, T_ / 128, B_), dim3(512), 0, stream>>>(Qp, Kp, Vt, adj, mask, aout);
  // output projection weights into dead Qp region
  cvt_f32_bf16<<<dim3(1024 * 1024 / 4 / 256), blk, 0, stream>>>(W_out, wo_bf, 1024 * 1024);
  // output projection: C fp32 -> d_out; fp32 bias direct
  gemm_bt_bias<1><<<dim3(D_ / 128, (B_ * T_) / 128), dim3(512), 0, stream>>>(
      aout, wo_bf, b_out, d_out, nullptr, nullptr, B_ * T_, D_, D_);
}